// Round 8
// baseline (163.090 us; speedup 1.0000x reference)
//
#include <hip/hip_runtime.h>
#include <hip/hip_bf16.h>

// Problem: B=4, T=4096, C=512, H=64 single-head causal attention, fp32 I/O.
#define Tt 4096

typedef __bf16 bf16;
typedef __attribute__((ext_vector_type(8))) __bf16 bf16x8;
typedef __attribute__((ext_vector_type(4))) __bf16 bf16x4;
typedef __attribute__((ext_vector_type(4))) float f32x4;

// ---------------------------------------------------------------------------
// ws layout (bytes) — ws_size is 256 MiB (fill evidence), plenty:
//   wt     bf16 [3][64][512]    @ 0         (196608)
//   K      bf16 [B*T][64]       @ 196608    (2097152)
//   Q      bf16 [B*T][64]       @ 2293760   (2097152)  pre-scaled by 1/sqrt(512)
//   VT     bf16 [B][64][T]      @ 4390912   (2097152)  V transposed
//   Opart  bf16 [1088][128][64] @ 6488064   (17825792) unnormalized partials
//   Lpart  f32  [1088][128]     @ 24313856  (557056)
// ---------------------------------------------------------------------------

// ---------------------------------------------------------------------------
// Kernel 0: W [512][64] fp32 -> Wt [3][64][512] bf16 (Q scaled by 1/sqrt(512))
// ---------------------------------------------------------------------------
__global__ __launch_bounds__(256) void wt_kernel(const float* __restrict__ Wk,
                                                 const float* __restrict__ Wq,
                                                 const float* __restrict__ Wv,
                                                 bf16* __restrict__ wt) {
  int idx = blockIdx.x * 256 + threadIdx.x;  // [3][64][512]
  int mat = idx >> 15;
  int rem = idx & 32767;
  int n = rem >> 9;
  int k = rem & 511;
  const float* W = (mat == 0) ? Wk : (mat == 1) ? Wq : Wv;
  float v = W[k * 64 + n];
  if (mat == 1) v *= 0.044194173824159216f;  // 1/sqrt(512) folded into Q
  wt[idx] = (bf16)v;
}

// ---------------------------------------------------------------------------
// Kernel 1: QKV projection (proven r4/r7 version, unchanged).
// ---------------------------------------------------------------------------
__global__ __launch_bounds__(256) void proj_kernel(const float* __restrict__ x,
                                                   const bf16* __restrict__ wt,
                                                   bf16* __restrict__ Kb,
                                                   bf16* __restrict__ Qb,
                                                   bf16* __restrict__ VTb) {
  __shared__ __attribute__((aligned(16))) bf16 xs[16][520];
  int tid = threadIdx.x;
  int row0 = blockIdx.x * 16;

  int sr = tid >> 4, sc = (tid & 15) * 4;
  const float* xr = x + (size_t)(row0 + sr) * 512;
#pragma unroll
  for (int j = 0; j < 8; ++j) {
    f32x4 a = *(const f32x4*)(xr + sc + j * 64);
    bf16x4 h;
#pragma unroll
    for (int e = 0; e < 4; ++e) h[e] = (bf16)a[e];
    *(bf16x4*)&xs[sr][sc + j * 64] = h;
  }
  __syncthreads();

  int wave = tid >> 6, lane = tid & 63, m = lane & 15, quad = lane >> 4;
  f32x4 acc[3];
#pragma unroll
  for (int i = 0; i < 3; ++i) acc[i] = (f32x4){0.f, 0.f, 0.f, 0.f};

#pragma unroll 4
  for (int kk = 0; kk < 512; kk += 32) {
    bf16x8 af = *(const bf16x8*)&xs[m][kk + quad * 8];
#pragma unroll
    for (int i = 0; i < 3; ++i) {
      int nt = wave * 3 + i;
      bf16x8 bfr = *(const bf16x8*)(wt + (nt >> 2) * 32768 +
                                    (((nt & 3) * 16) + m) * 512 + kk + quad * 8);
      acc[i] = __builtin_amdgcn_mfma_f32_16x16x32_bf16(af, bfr, acc[i], 0, 0, 0);
    }
  }

  int b = row0 >> 12, tloc = row0 & 4095;
#pragma unroll
  for (int i = 0; i < 3; ++i) {
    int nt = wave * 3 + i, mat = nt >> 2, n0 = (nt & 3) * 16;
    if (mat == 2) {  // VT[b][d][t]
      bf16x4 pv;
#pragma unroll
      for (int r = 0; r < 4; ++r) pv[r] = (bf16)acc[i][r];
      *(bf16x4*)&VTb[((size_t)b * 64 + n0 + m) * 4096 + tloc + quad * 4] = pv;
    } else {
      bf16* dst = (mat == 0) ? Kb : Qb;
#pragma unroll
      for (int r = 0; r < 4; ++r)
        dst[(size_t)(row0 + quad * 4 + r) * 64 + n0 + m] = (bf16)acc[i][r];
    }
  }
}

// ---------------------------------------------------------------------------
// Kernel 2: flash attention, Br=128 (each wave 32 Q-rows as 2 row-frags),
// Bc=64 tiles, KV chunk 256. 1088 blocks, batch-interleaved heavy-first.
// Single barrier per tile: double-buffered K/V LDS; staging ownership =
// waves 0/1 -> Kt halves, waves 2/3 -> Vt halves; P-scratch = own staging
// region of the INACTIVE buffer (in-wave LDS ordering only).
// No running max (scores bounded ~|3|); l via ones-MFMA; plain-sum combine.
// ---------------------------------------------------------------------------
__global__ __launch_bounds__(256, 3) void attn_kernel(const bf16* __restrict__ Qb,
                                                      const bf16* __restrict__ Kb,
                                                      const bf16* __restrict__ VTb,
                                                      bf16* __restrict__ Opart,
                                                      float* __restrict__ Lpart,
                                                      float* __restrict__ out) {
  __shared__ __attribute__((aligned(16))) bf16 Kt[2][64][72];  // [buf][kv][d]
  __shared__ __attribute__((aligned(16))) bf16 Vt[2][64][72];  // [buf][d][kv]

  int tid = threadIdx.x, wave = tid >> 6, lane = tid & 63;
  int m = lane & 15, quad = lane >> 4, kq = quad * 8;

  // unit decode: 272 units/batch; qi in [0,32) of 128 rows; chunks of 256 kv.
  int uu = 1087 - (int)blockIdx.x;
  int b = uu & 3;       // batch-interleaved
  int u2 = uu >> 2;     // heavy-first within batch
  int qi = 0;
  for (;;) {
    int sz = (qi >> 1) + 1;
    if (u2 < sz) break;
    u2 -= sz;
    ++qi;
  }
  int c = u2;
  int g = qi >> 1;
  int t0 = qi * 128;
  int s_beg = c * 256;
  int niter = (min(s_beg + 256, t0 + 128) - s_beg) >> 6;  // 1..4

  // Q fragments: wave covers rows [t0+wave*32, +32), 2 row-frags x 2 k-chunks
  const bf16* Qp = Qb + ((size_t)b * Tt + t0 + wave * 32) * 64;
  bf16x8 aq[2][2];
#pragma unroll
  for (int rf = 0; rf < 2; ++rf)
#pragma unroll
    for (int ch = 0; ch < 2; ++ch)
      aq[rf][ch] = *(const bf16x8*)(Qp + (size_t)(rf * 16 + m) * 64 + ch * 32 + kq);

  bf16x8 onesb;
#pragma unroll
  for (int j = 0; j < 8; ++j) onesb[j] = (bf16)1.0f;

  f32x4 o[2][4];
#pragma unroll
  for (int rf = 0; rf < 2; ++rf)
#pragma unroll
    for (int dt = 0; dt < 4; ++dt) o[rf][dt] = (f32x4){0.f, 0.f, 0.f, 0.f};
  f32x4 ls[2];
  ls[0] = ls[1] = (f32x4){0.f, 0.f, 0.f, 0.f};

  const bf16* Kbase = Kb + (size_t)b * Tt * 64;
  const bf16* VTbase = VTb + (size_t)b * 64 * Tt;

  // staging roles: lane sr=row-in-region(0..31), sh=64B half
  int sr = lane >> 1, sh = (lane & 1) * 32;
  bool isK = wave < 2;
  int rowoff = (wave & 1) * 32;

  // stage tile 0 into buf 0 (own region only)
  {
    const bf16* src = isK ? (Kbase + (size_t)(s_beg + rowoff + sr) * 64 + sh)
                          : (VTbase + (size_t)(rowoff + sr) * Tt + s_beg + sh);
    bf16* dst = isK ? &Kt[0][rowoff + sr][sh] : &Vt[0][rowoff + sr][sh];
#pragma unroll
    for (int j = 0; j < 4; ++j)
      *(bf16x8*)(dst + j * 8) = *(const bf16x8*)(src + j * 8);
  }

  bf16x8 pf[4];
  for (int i = 0; i < niter; ++i) {
    int s0 = s_beg + i * 64;
    int cur = i & 1, nxt = cur ^ 1;
    __syncthreads();  // publishes buf[cur]; frees buf[nxt] (P + staging)

    if (i + 1 < niter) {  // prefetch next tile; lands during compute
      int sn = s0 + 64;
      const bf16* src = isK ? (Kbase + (size_t)(sn + rowoff + sr) * 64 + sh)
                            : (VTbase + (size_t)(rowoff + sr) * Tt + sn + sh);
#pragma unroll
      for (int j = 0; j < 4; ++j) pf[j] = *(const bf16x8*)(src + j * 8);
    }

    // ---- S = Q K^T  (B-frags shared across the 2 row-frags) ----
    f32x4 s[2][4];
#pragma unroll
    for (int nt = 0; nt < 4; ++nt) {
      bf16x8 b0 = *(const bf16x8*)&Kt[cur][nt * 16 + m][kq];
      bf16x8 b1 = *(const bf16x8*)&Kt[cur][nt * 16 + m][32 + kq];
#pragma unroll
      for (int rf = 0; rf < 2; ++rf) {
        f32x4 sa = (f32x4){0.f, 0.f, 0.f, 0.f};
        sa = __builtin_amdgcn_mfma_f32_16x16x32_bf16(aq[rf][0], b0, sa, 0, 0, 0);
        sa = __builtin_amdgcn_mfma_f32_16x16x32_bf16(aq[rf][1], b1, sa, 0, 0, 0);
        s[rf][nt] = sa;
      }
    }

    // ---- causal mask (tiles overlapping the diagonal band) ----
    if (s0 + 64 > t0) {
#pragma unroll
      for (int rf = 0; rf < 2; ++rf)
#pragma unroll
        for (int nt = 0; nt < 4; ++nt) {
          int col = s0 + nt * 16 + m;
#pragma unroll
          for (int r = 0; r < 4; ++r) {
            int row = t0 + wave * 32 + rf * 16 + quad * 4 + r;
            if (col > row) s[rf][nt][r] = -1e30f;
          }
        }
    }

    // ---- P = exp(S) -> own staging region of inactive buffer ----
    bf16(*Pl)[72] = isK ? &Kt[nxt][rowoff] : &Vt[nxt][rowoff];
#pragma unroll
    for (int rf = 0; rf < 2; ++rf)
#pragma unroll
      for (int nt = 0; nt < 4; ++nt)
#pragma unroll
        for (int r = 0; r < 4; ++r)
          Pl[rf * 16 + quad * 4 + r][nt * 16 + m] = (bf16)__expf(s[rf][nt][r]);

    // ---- O += P V ; l += P * ones ----
    bf16x8 ap[2][2];
#pragma unroll
    for (int rf = 0; rf < 2; ++rf)
#pragma unroll
      for (int ch = 0; ch < 2; ++ch)
        ap[rf][ch] = *(const bf16x8*)&Pl[rf * 16 + m][ch * 32 + kq];
#pragma unroll
    for (int rf = 0; rf < 2; ++rf)
#pragma unroll
      for (int ch = 0; ch < 2; ++ch)
        ls[rf] = __builtin_amdgcn_mfma_f32_16x16x32_bf16(ap[rf][ch], onesb, ls[rf], 0, 0, 0);
#pragma unroll
    for (int dt = 0; dt < 4; ++dt) {
      bf16x8 v0 = *(const bf16x8*)&Vt[cur][dt * 16 + m][kq];
      bf16x8 v1 = *(const bf16x8*)&Vt[cur][dt * 16 + m][32 + kq];
#pragma unroll
      for (int rf = 0; rf < 2; ++rf) {
        o[rf][dt] = __builtin_amdgcn_mfma_f32_16x16x32_bf16(ap[rf][0], v0, o[rf][dt], 0, 0, 0);
        o[rf][dt] = __builtin_amdgcn_mfma_f32_16x16x32_bf16(ap[rf][1], v1, o[rf][dt], 0, 0, 0);
      }
    }

    // ---- stage next tile into own region of buf[nxt] (after P reads) ----
    if (i + 1 < niter) {
      bf16* dst = isK ? &Kt[nxt][rowoff + sr][sh] : &Vt[nxt][rowoff + sr][sh];
#pragma unroll
      for (int j = 0; j < 4; ++j) *(bf16x8*)(dst + j * 8) = pf[j];
    }
  }

  // ---- epilogue ----
  if (g == 0) {  // qi 0,1: single chunk -> normalized direct write
    float* op = out + ((size_t)b * Tt + t0 + wave * 32) * 64;
#pragma unroll
    for (int rf = 0; rf < 2; ++rf)
#pragma unroll
      for (int r = 0; r < 4; ++r) {
        float inv = 1.0f / ls[rf][r];
        int row = rf * 16 + quad * 4 + r;
#pragma unroll
        for (int dt = 0; dt < 4; ++dt)
          op[(size_t)row * 64 + dt * 16 + m] = o[rf][dt][r] * inv;
      }
  } else {
    int pbase = (qi & 1) ? (g + 1) * (g + 1) : g * (g + 1);
    int p = b * 272 + pbase + c;
    bf16* Op = Opart + (size_t)p * 8192;
#pragma unroll
    for (int rf = 0; rf < 2; ++rf)
#pragma unroll
      for (int r = 0; r < 4; ++r) {
        int row = wave * 32 + rf * 16 + quad * 4 + r;
#pragma unroll
        for (int dt = 0; dt < 4; ++dt)
          Op[row * 64 + dt * 16 + m] = (bf16)o[rf][dt][r];
      }
    if (m == 0) {
#pragma unroll
      for (int rf = 0; rf < 2; ++rf)
#pragma unroll
        for (int r = 0; r < 4; ++r)
          Lpart[p * 128 + wave * 32 + rf * 16 + quad * 4 + r] = ls[rf][r];
    }
  }
}

// ---------------------------------------------------------------------------
// Kernel 3: combine partials (plain sums). qi >= 2 only; 480 blocks.
// ---------------------------------------------------------------------------
__global__ __launch_bounds__(256) void combine_kernel(const bf16* __restrict__ Opart,
                                                      const float* __restrict__ Lpart,
                                                      float* __restrict__ out) {
  int blk = blockIdx.x;
  int b = blk / 120, rem = blk % 120;
  int qi = 2 + (rem >> 2), rq = rem & 3;
  int g = qi >> 1, nc = g + 1;
  int pbase = (qi & 1) ? (g + 1) * (g + 1) : g * (g + 1);
  int pb = b * 272 + pbase;
  int col = threadIdx.x & 63, rl = threadIdx.x >> 6;
#pragma unroll
  for (int pass = 0; pass < 8; ++pass) {
    int row = rq * 32 + pass * 4 + rl;  // 0..127
    float L = 0.f, acc = 0.f;
    for (int cc = 0; cc < nc; ++cc) {
      L += Lpart[(pb + cc) * 128 + row];
      acc += (float)Opart[(size_t)(pb + cc) * 8192 + row * 64 + col];
    }
    out[((size_t)b * Tt + qi * 128 + row) * 64 + col] = acc / L;
  }
}

// ---------------------------------------------------------------------------
extern "C" void kernel_launch(void* const* d_in, const int* in_sizes, int n_in,
                              void* d_out, int out_size, void* d_ws, size_t ws_size,
                              hipStream_t stream) {
  const float* x = (const float*)d_in[0];
  const float* Wk = (const float*)d_in[1];
  const float* Wq = (const float*)d_in[2];
  const float* Wv = (const float*)d_in[3];
  float* out = (float*)d_out;

  char* w = (char*)d_ws;
  bf16* wt = (bf16*)w;                      // 196608
  bf16* Kb = (bf16*)(w + 196608);           // 2097152
  bf16* Qb = (bf16*)(w + 2293760);          // 2097152
  bf16* VTb = (bf16*)(w + 4390912);         // 2097152
  bf16* Opart = (bf16*)(w + 6488064);       // 17825792
  float* Lpart = (float*)(w + 24313856);    // 557056

  wt_kernel<<<384, 256, 0, stream>>>(Wk, Wq, Wv, wt);
  proj_kernel<<<1024, 256, 0, stream>>>(x, wt, Kb, Qb, VTb);
  attn_kernel<<<1088, 256, 0, stream>>>(Qb, Kb, VTb, Opart, Lpart, out);
  combine_kernel<<<480, 256, 0, stream>>>(Opart, Lpart, out);
}

// Round 9
// 138.697 us; speedup vs baseline: 1.1759x; 1.1759x over previous
//
#include <hip/hip_runtime.h>
#include <hip/hip_bf16.h>

// Problem: B=4, T=4096, C=512, H=64 single-head causal attention, fp32 I/O.
#define Tt 4096

typedef __bf16 bf16;
typedef __attribute__((ext_vector_type(8))) __bf16 bf16x8;
typedef __attribute__((ext_vector_type(4))) __bf16 bf16x4;
typedef __attribute__((ext_vector_type(4))) float f32x4;

// ---------------------------------------------------------------------------
// ws layout (bytes):
//   wt     bf16 [3][64][512]    @ 0         (196608)
//   K      bf16 [B*T][64]       @ 196608    (2097152)
//   Q      bf16 [B*T][64]       @ 2293760   (2097152)  pre-scaled by log2e/sqrt(512)
//   VT     bf16 [B][64][T]      @ 4390912   (2097152)  V transposed
//   Opart  bf16 [1152][64][64]  @ 6488064   (9437184)  unnormalized partials
//   Lpart  f32  [1152][64]      @ 15925248  (294912)
// total ~16.2 MB
// ---------------------------------------------------------------------------

// ---------------------------------------------------------------------------
// Kernel 0: W [512][64] fp32 -> Wt [3][64][512] bf16.
// Q scaled by log2(e)/sqrt(512) so P = exp2(S) directly.
// ---------------------------------------------------------------------------
__global__ __launch_bounds__(256) void wt_kernel(const float* __restrict__ Wk,
                                                 const float* __restrict__ Wq,
                                                 const float* __restrict__ Wv,
                                                 bf16* __restrict__ wt) {
  int idx = blockIdx.x * 256 + threadIdx.x;  // [3][64][512]
  int mat = idx >> 15;
  int rem = idx & 32767;
  int n = rem >> 9;
  int k = rem & 511;
  const float* W = (mat == 0) ? Wk : (mat == 1) ? Wq : Wv;
  float v = W[k * 64 + n];
  if (mat == 1) v *= 0.06375871547336652f;  // log2(e)/sqrt(512) folded into Q
  wt[idx] = (bf16)v;
}

// ---------------------------------------------------------------------------
// Kernel 1: QKV projection (proven r4/r7 version, unchanged).
// ---------------------------------------------------------------------------
__global__ __launch_bounds__(256) void proj_kernel(const float* __restrict__ x,
                                                   const bf16* __restrict__ wt,
                                                   bf16* __restrict__ Kb,
                                                   bf16* __restrict__ Qb,
                                                   bf16* __restrict__ VTb) {
  __shared__ __attribute__((aligned(16))) bf16 xs[16][520];
  int tid = threadIdx.x;
  int row0 = blockIdx.x * 16;

  int sr = tid >> 4, sc = (tid & 15) * 4;
  const float* xr = x + (size_t)(row0 + sr) * 512;
#pragma unroll
  for (int j = 0; j < 8; ++j) {
    f32x4 a = *(const f32x4*)(xr + sc + j * 64);
    bf16x4 h;
#pragma unroll
    for (int e = 0; e < 4; ++e) h[e] = (bf16)a[e];
    *(bf16x4*)&xs[sr][sc + j * 64] = h;
  }
  __syncthreads();

  int wave = tid >> 6, lane = tid & 63, m = lane & 15, quad = lane >> 4;
  f32x4 acc[3];
#pragma unroll
  for (int i = 0; i < 3; ++i) acc[i] = (f32x4){0.f, 0.f, 0.f, 0.f};

#pragma unroll 4
  for (int kk = 0; kk < 512; kk += 32) {
    bf16x8 af = *(const bf16x8*)&xs[m][kk + quad * 8];
#pragma unroll
    for (int i = 0; i < 3; ++i) {
      int nt = wave * 3 + i;
      bf16x8 bfr = *(const bf16x8*)(wt + (nt >> 2) * 32768 +
                                    (((nt & 3) * 16) + m) * 512 + kk + quad * 8);
      acc[i] = __builtin_amdgcn_mfma_f32_16x16x32_bf16(af, bfr, acc[i], 0, 0, 0);
    }
  }

  int b = row0 >> 12, tloc = row0 & 4095;
#pragma unroll
  for (int i = 0; i < 3; ++i) {
    int nt = wave * 3 + i, mat = nt >> 2, n0 = (nt & 3) * 16;
    if (mat == 2) {  // VT[b][d][t]
      bf16x4 pv;
#pragma unroll
      for (int r = 0; r < 4; ++r) pv[r] = (bf16)acc[i][r];
      *(bf16x4*)&VTb[((size_t)b * 64 + n0 + m) * 4096 + tloc + quad * 4] = pv;
    } else {
      bf16* dst = (mat == 0) ? Kb : Qb;
#pragma unroll
      for (int r = 0; r < 4; ++r)
        dst[(size_t)(row0 + quad * 4 + r) * 64 + n0 + m] = (bf16)acc[i][r];
    }
  }
}

// ---------------------------------------------------------------------------
// Kernel 2: flash attention, split-KV (r7 structure, Br=64, chunk 512).
// NEW: S^T via swapped MFMA operands (A=K-frag, B=Q-frag — byte-identical
// LDS/register reads). C-layout of S^T: col=q-row=lane&15, row=kv=quad*4+r,
// so each lane holds 4 CONSECUTIVE kv for fixed q-row -> P spills as ONE
// ds_write_b64 per nt (4 packed stores/lane/tile, was 16 scalar b16).
// P = exp2(S) (log2e folded into Q). l via ones-MFMA; plain-sum combine.
// ---------------------------------------------------------------------------
__global__ __launch_bounds__(256, 4) void attn_kernel(const bf16* __restrict__ Qb,
                                                      const bf16* __restrict__ Kb,
                                                      const bf16* __restrict__ VTb,
                                                      bf16* __restrict__ Opart,
                                                      float* __restrict__ Lpart,
                                                      float* __restrict__ out) {
  __shared__ __attribute__((aligned(16))) bf16 Kt[2][64][72];  // [buf][kv][d]
  __shared__ __attribute__((aligned(16))) bf16 Vt[2][64][72];  // [buf][d][kv]

  int tid = threadIdx.x, wave = tid >> 6, lane = tid & 63;
  int m = lane & 15, quad = lane >> 4, kq = quad * 8;
  int r_ = tid >> 2, seg = tid & 3;  // staging: wave w owns rows [16w,16w+16)

  // unit decode: per batch 288 units; group g = qi>>3 has 8*(g+1) units
  int uu = 1151 - (int)blockIdx.x;
  int b = uu / 288, u2 = uu % 288;
  int g = 0;
  while (u2 >= 4 * (g + 1) * (g + 2)) ++g;
  int rr = u2 - 4 * g * (g + 1);
  int qi = 8 * g + rr / (g + 1);
  int c = rr % (g + 1);
  int t0 = qi * 64;
  int s_beg = c * 512;
  int niter = (min(s_beg + 512, t0 + 64) - s_beg) >> 6;

  const bf16* Qp = Qb + ((size_t)b * Tt + t0 + wave * 16 + m) * 64;
  bf16x8 aq0 = *(const bf16x8*)(Qp + kq);
  bf16x8 aq1 = *(const bf16x8*)(Qp + 32 + kq);

  bf16x8 onesb;
#pragma unroll
  for (int j = 0; j < 8; ++j) onesb[j] = (bf16)1.0f;

  f32x4 o[4];
#pragma unroll
  for (int i = 0; i < 4; ++i) o[i] = (f32x4){0.f, 0.f, 0.f, 0.f};
  f32x4 lsum = (f32x4){0.f, 0.f, 0.f, 0.f};

  const bf16* Kbase = Kb + (size_t)b * (Tt * 64);
  const bf16* VTbase = VTb + (size_t)b * (64 * Tt);

  // stage tile 0 into buf 0
  {
    const bf16* ks = Kbase + (size_t)(s_beg + r_) * 64 + seg * 16;
    bf16x8 k0 = *(const bf16x8*)ks;
    bf16x8 k1 = *(const bf16x8*)(ks + 8);
    const bf16* vs = VTbase + (size_t)r_ * Tt + s_beg + seg * 16;
    bf16x8 v0 = *(const bf16x8*)vs;
    bf16x8 v1 = *(const bf16x8*)(vs + 8);
    *(bf16x8*)&Kt[0][r_][seg * 16] = k0;
    *(bf16x8*)&Kt[0][r_][seg * 16 + 8] = k1;
    *(bf16x8*)&Vt[0][r_][seg * 16] = v0;
    *(bf16x8*)&Vt[0][r_][seg * 16 + 8] = v1;
  }

  bf16x8 k0, k1, v0, v1;
  for (int i = 0; i < niter; ++i) {
    int s0 = s_beg + i * 64;
    int cur = i & 1, nxt = cur ^ 1;
    __syncthreads();  // publishes buf[cur]; frees buf[nxt] for P/staging

    if (i + 1 < niter) {  // issue prefetch now; lands during compute
      int sn = s0 + 64;
      const bf16* ks2 = Kbase + (size_t)(sn + r_) * 64 + seg * 16;
      k0 = *(const bf16x8*)ks2;
      k1 = *(const bf16x8*)(ks2 + 8);
      const bf16* vs2 = VTbase + (size_t)r_ * Tt + sn + seg * 16;
      v0 = *(const bf16x8*)vs2;
      v1 = *(const bf16x8*)(vs2 + 8);
    }

    // ---- S^T = K Q^T (operand-swapped: row=kv=quad*4+r, col=q=m) ----
    f32x4 s[4];
#pragma unroll
    for (int nt = 0; nt < 4; ++nt) {
      bf16x8 b0 = *(const bf16x8*)&Kt[cur][nt * 16 + m][kq];
      bf16x8 b1 = *(const bf16x8*)&Kt[cur][nt * 16 + m][32 + kq];
      f32x4 sa = (f32x4){0.f, 0.f, 0.f, 0.f};
      sa = __builtin_amdgcn_mfma_f32_16x16x32_bf16(b0, aq0, sa, 0, 0, 0);
      sa = __builtin_amdgcn_mfma_f32_16x16x32_bf16(b1, aq1, sa, 0, 0, 0);
      s[nt] = sa;
    }

    // ---- causal mask (diagonal tile only): mask where kv > q ----
    if (s0 + 64 > t0) {
      int qrow = t0 + wave * 16 + m;
#pragma unroll
      for (int nt = 0; nt < 4; ++nt) {
#pragma unroll
        for (int r = 0; r < 4; ++r) {
          int kv = s0 + nt * 16 + quad * 4 + r;
          if (kv > qrow) s[nt][r] = -1e30f;
        }
      }
    }

    // ---- P = exp2(S) -> packed b64 store: P[q=m][kv], 4 consecutive kv ----
    bf16(*Pl)[72] = &Kt[nxt][wave * 16];
#pragma unroll
    for (int nt = 0; nt < 4; ++nt) {
      bf16x4 pv;
#pragma unroll
      for (int r = 0; r < 4; ++r) pv[r] = (bf16)exp2f(s[nt][r]);
      *(bf16x4*)&Pl[m][nt * 16 + quad * 4] = pv;
    }

    // ---- O += P V ; l += P * ones (in-wave P round-trip, no barrier) ----
#pragma unroll
    for (int ch = 0; ch < 2; ++ch) {
      bf16x8 ap = *(const bf16x8*)&Pl[m][ch * 32 + kq];
      lsum = __builtin_amdgcn_mfma_f32_16x16x32_bf16(ap, onesb, lsum, 0, 0, 0);
#pragma unroll
      for (int nt = 0; nt < 4; ++nt) {
        bf16x8 bv = *(const bf16x8*)&Vt[cur][nt * 16 + m][ch * 32 + kq];
        o[nt] = __builtin_amdgcn_mfma_f32_16x16x32_bf16(ap, bv, o[nt], 0, 0, 0);
      }
    }

    // ---- stage next tile into buf[nxt] own-wave rows (after P consumed) ----
    if (i + 1 < niter) {
      *(bf16x8*)&Kt[nxt][r_][seg * 16] = k0;
      *(bf16x8*)&Kt[nxt][r_][seg * 16 + 8] = k1;
      *(bf16x8*)&Vt[nxt][r_][seg * 16] = v0;
      *(bf16x8*)&Vt[nxt][r_][seg * 16 + 8] = v1;
    }
  }

  // ---- epilogue ----
  int rl0 = wave * 16 + quad * 4;
  if (g == 0) {  // single chunk: write normalized output directly
    float* op = out + ((size_t)b * Tt + t0) * 64;
#pragma unroll
    for (int r = 0; r < 4; ++r) {
      float inv = 1.0f / lsum[r];
#pragma unroll
      for (int nt = 0; nt < 4; ++nt)
        op[(size_t)(rl0 + r) * 64 + nt * 16 + m] = o[nt][r] * inv;
    }
  } else {
    int p = b * 288 + 4 * g * (g + 1) + (qi - 8 * g) * (g + 1) + c;
    bf16* Op = Opart + (size_t)p * 4096;
#pragma unroll
    for (int r = 0; r < 4; ++r)
#pragma unroll
      for (int nt = 0; nt < 4; ++nt)
        Op[(rl0 + r) * 64 + nt * 16 + m] = (bf16)o[nt][r];
    if (m == 0) {
#pragma unroll
      for (int r = 0; r < 4; ++r) Lpart[p * 64 + rl0 + r] = lsum[r];
    }
  }
}

// ---------------------------------------------------------------------------
// Kernel 3: combine partials (plain sums). qi >= 8 only; 896 blocks.
// ---------------------------------------------------------------------------
__global__ __launch_bounds__(256) void combine_kernel(const bf16* __restrict__ Opart,
                                                      const float* __restrict__ Lpart,
                                                      float* __restrict__ out) {
  int blk = blockIdx.x;
  int b = blk / 224, rem = blk % 224;
  int qi = 8 + (rem >> 2), rq = rem & 3;
  int g = qi >> 3, nc = g + 1;
  int pb = b * 288 + 4 * g * (g + 1) + (qi - 8 * g) * (g + 1);
  int t = threadIdx.x, col = t & 63, rl = t >> 6;
#pragma unroll
  for (int rr = 0; rr < 4; ++rr) {
    int row64 = rq * 16 + rl * 4 + rr;
    float L = 0.f, acc = 0.f;
    for (int cc = 0; cc < nc; ++cc) {
      L += Lpart[(pb + cc) * 64 + row64];
      acc += (float)Opart[(size_t)(pb + cc) * 4096 + row64 * 64 + col];
    }
    out[((size_t)b * Tt + qi * 64 + row64) * 64 + col] = acc / L;
  }
}

// ---------------------------------------------------------------------------
extern "C" void kernel_launch(void* const* d_in, const int* in_sizes, int n_in,
                              void* d_out, int out_size, void* d_ws, size_t ws_size,
                              hipStream_t stream) {
  const float* x = (const float*)d_in[0];
  const float* Wk = (const float*)d_in[1];
  const float* Wq = (const float*)d_in[2];
  const float* Wv = (const float*)d_in[3];
  float* out = (float*)d_out;

  char* w = (char*)d_ws;
  bf16* wt = (bf16*)w;                      // 196608
  bf16* Kb = (bf16*)(w + 196608);           // 2097152
  bf16* Qb = (bf16*)(w + 2293760);          // 2097152
  bf16* VTb = (bf16*)(w + 4390912);         // 2097152
  bf16* Opart = (bf16*)(w + 6488064);       // 9437184
  float* Lpart = (float*)(w + 15925248);    // 294912

  wt_kernel<<<384, 256, 0, stream>>>(Wk, Wq, Wv, wt);
  proj_kernel<<<1024, 256, 0, stream>>>(x, wt, Kb, Qb, VTb);
  attn_kernel<<<1152, 256, 0, stream>>>(Qb, Kb, VTb, Opart, Lpart, out);
  combine_kernel<<<896, 256, 0, stream>>>(Opart, Lpart, out);
}

// Round 11
// 138.203 us; speedup vs baseline: 1.1801x; 1.0036x over previous
//
#include <hip/hip_runtime.h>
#include <hip/hip_bf16.h>

// Problem: B=4, T=4096, C=512, H=64 single-head causal attention, fp32 I/O.
#define Tt 4096

typedef __bf16 bf16;
typedef __attribute__((ext_vector_type(8))) __bf16 bf16x8;
typedef __attribute__((ext_vector_type(4))) __bf16 bf16x4;
typedef __attribute__((ext_vector_type(4))) float f32x4;

// ---------------------------------------------------------------------------
// ws layout (bytes):
//   wt     bf16 [3][64][512]    @ 0         (196608)
//   K      bf16 [B*T][64]       @ 196608    (2097152)
//   Q      bf16 [B*T][64]       @ 2293760   (2097152)  pre-scaled by log2e/sqrt(512)
//   VT     bf16 [B][64][T]      @ 4390912   (2097152)  V transposed
//   Opart  bf16 [1152][64][64]  @ 6488064   (9437184)  unnormalized partials
//   Lpart  f32  [1152][64]      @ 15925248  (294912)
// total ~16.2 MB
// ---------------------------------------------------------------------------

// ---------------------------------------------------------------------------
// Kernel 0: W [512][64] fp32 -> Wt [3][64][512] bf16.
// Q scaled by log2(e)/sqrt(512) so P = exp2(S) directly.
// ---------------------------------------------------------------------------
__global__ __launch_bounds__(256) void wt_kernel(const float* __restrict__ Wk,
                                                 const float* __restrict__ Wq,
                                                 const float* __restrict__ Wv,
                                                 bf16* __restrict__ wt) {
  int idx = blockIdx.x * 256 + threadIdx.x;  // [3][64][512]
  int mat = idx >> 15;
  int rem = idx & 32767;
  int n = rem >> 9;
  int k = rem & 511;
  const float* W = (mat == 0) ? Wk : (mat == 1) ? Wq : Wv;
  float v = W[k * 64 + n];
  if (mat == 1) v *= 0.06375871547336652f;  // log2(e)/sqrt(512) folded into Q
  wt[idx] = (bf16)v;
}

// ---------------------------------------------------------------------------
// Kernel 1: QKV projection (proven r4/r7/r9 version: 16 rows/block, 1024
// blocks). x tile staged in LDS (bf16, pad 520 -> conflict-free); each wave
// owns 3 of the 12 output frags over full K=512. V written transposed via
// packed 8B t-contiguous stores.
// ---------------------------------------------------------------------------
__global__ __launch_bounds__(256) void proj_kernel(const float* __restrict__ x,
                                                   const bf16* __restrict__ wt,
                                                   bf16* __restrict__ Kb,
                                                   bf16* __restrict__ Qb,
                                                   bf16* __restrict__ VTb) {
  __shared__ __attribute__((aligned(16))) bf16 xs[16][520];
  int tid = threadIdx.x;
  int row0 = blockIdx.x * 16;

  int sr = tid >> 4, sc = (tid & 15) * 4;
  const float* xr = x + (size_t)(row0 + sr) * 512;
#pragma unroll
  for (int j = 0; j < 8; ++j) {
    f32x4 a = *(const f32x4*)(xr + sc + j * 64);
    bf16x4 h;
#pragma unroll
    for (int e = 0; e < 4; ++e) h[e] = (bf16)a[e];
    *(bf16x4*)&xs[sr][sc + j * 64] = h;
  }
  __syncthreads();

  int wave = tid >> 6, lane = tid & 63, m = lane & 15, quad = lane >> 4;
  f32x4 acc[3];
#pragma unroll
  for (int i = 0; i < 3; ++i) acc[i] = (f32x4){0.f, 0.f, 0.f, 0.f};

#pragma unroll 4
  for (int kk = 0; kk < 512; kk += 32) {
    bf16x8 af = *(const bf16x8*)&xs[m][kk + quad * 8];
#pragma unroll
    for (int i = 0; i < 3; ++i) {
      int nt = wave * 3 + i;
      bf16x8 bfr = *(const bf16x8*)(wt + (nt >> 2) * 32768 +
                                    (((nt & 3) * 16) + m) * 512 + kk + quad * 8);
      acc[i] = __builtin_amdgcn_mfma_f32_16x16x32_bf16(af, bfr, acc[i], 0, 0, 0);
    }
  }

  int b = row0 >> 12, tloc = row0 & 4095;
#pragma unroll
  for (int i = 0; i < 3; ++i) {
    int nt = wave * 3 + i, mat = nt >> 2, n0 = (nt & 3) * 16;
    if (mat == 2) {  // VT[b][d][t]
      bf16x4 pv;
#pragma unroll
      for (int r = 0; r < 4; ++r) pv[r] = (bf16)acc[i][r];
      *(bf16x4*)&VTb[((size_t)b * 64 + n0 + m) * 4096 + tloc + quad * 4] = pv;
    } else {
      bf16* dst = (mat == 0) ? Kb : Qb;
#pragma unroll
      for (int r = 0; r < 4; ++r)
        dst[(size_t)(row0 + quad * 4 + r) * 64 + n0 + m] = (bf16)acc[i][r];
    }
  }
}

// ---------------------------------------------------------------------------
// Kernel 2: flash attention, split-KV (r9 version, tied-best: Br=64, chunk
// 512, 1152 blocks heavy-first). S^T via swapped MFMA operands; P spills as
// packed ds_write_b64 into the inactive K buffer's own-wave rows (in-wave
// ordering only); single barrier per tile; P = exp2(S); l via ones-MFMA.
// ---------------------------------------------------------------------------
__global__ __launch_bounds__(256, 4) void attn_kernel(const bf16* __restrict__ Qb,
                                                      const bf16* __restrict__ Kb,
                                                      const bf16* __restrict__ VTb,
                                                      bf16* __restrict__ Opart,
                                                      float* __restrict__ Lpart,
                                                      float* __restrict__ out) {
  __shared__ __attribute__((aligned(16))) bf16 Kt[2][64][72];  // [buf][kv][d]
  __shared__ __attribute__((aligned(16))) bf16 Vt[2][64][72];  // [buf][d][kv]

  int tid = threadIdx.x, wave = tid >> 6, lane = tid & 63;
  int m = lane & 15, quad = lane >> 4, kq = quad * 8;
  int r_ = tid >> 2, seg = tid & 3;  // staging: wave w owns rows [16w,16w+16)

  // unit decode: per batch 288 units; group g = qi>>3 has 8*(g+1) units
  int uu = 1151 - (int)blockIdx.x;
  int b = uu / 288, u2 = uu % 288;
  int g = 0;
  while (u2 >= 4 * (g + 1) * (g + 2)) ++g;
  int rr = u2 - 4 * g * (g + 1);
  int qi = 8 * g + rr / (g + 1);
  int c = rr % (g + 1);
  int t0 = qi * 64;
  int s_beg = c * 512;
  int niter = (min(s_beg + 512, t0 + 64) - s_beg) >> 6;

  const bf16* Qp = Qb + ((size_t)b * Tt + t0 + wave * 16 + m) * 64;
  bf16x8 aq0 = *(const bf16x8*)(Qp + kq);
  bf16x8 aq1 = *(const bf16x8*)(Qp + 32 + kq);

  bf16x8 onesb;
#pragma unroll
  for (int j = 0; j < 8; ++j) onesb[j] = (bf16)1.0f;

  f32x4 o[4];
#pragma unroll
  for (int i = 0; i < 4; ++i) o[i] = (f32x4){0.f, 0.f, 0.f, 0.f};
  f32x4 lsum = (f32x4){0.f, 0.f, 0.f, 0.f};

  const bf16* Kbase = Kb + (size_t)b * (Tt * 64);
  const bf16* VTbase = VTb + (size_t)b * (64 * Tt);

  // stage tile 0 into buf 0
  {
    const bf16* ks = Kbase + (size_t)(s_beg + r_) * 64 + seg * 16;
    bf16x8 k0 = *(const bf16x8*)ks;
    bf16x8 k1 = *(const bf16x8*)(ks + 8);
    const bf16* vs = VTbase + (size_t)r_ * Tt + s_beg + seg * 16;
    bf16x8 v0 = *(const bf16x8*)vs;
    bf16x8 v1 = *(const bf16x8*)(vs + 8);
    *(bf16x8*)&Kt[0][r_][seg * 16] = k0;
    *(bf16x8*)&Kt[0][r_][seg * 16 + 8] = k1;
    *(bf16x8*)&Vt[0][r_][seg * 16] = v0;
    *(bf16x8*)&Vt[0][r_][seg * 16 + 8] = v1;
  }

  bf16x8 k0, k1, v0, v1;
  for (int i = 0; i < niter; ++i) {
    int s0 = s_beg + i * 64;
    int cur = i & 1, nxt = cur ^ 1;
    __syncthreads();  // publishes buf[cur]; frees buf[nxt] for P/staging

    if (i + 1 < niter) {  // issue prefetch now; lands during compute
      int sn = s0 + 64;
      const bf16* ks2 = Kbase + (size_t)(sn + r_) * 64 + seg * 16;
      k0 = *(const bf16x8*)ks2;
      k1 = *(const bf16x8*)(ks2 + 8);
      const bf16* vs2 = VTbase + (size_t)r_ * Tt + sn + seg * 16;
      v0 = *(const bf16x8*)vs2;
      v1 = *(const bf16x8*)(vs2 + 8);
    }

    // ---- S^T = K Q^T (operand-swapped: row=kv=quad*4+r, col=q=m) ----
    f32x4 s[4];
#pragma unroll
    for (int nt = 0; nt < 4; ++nt) {
      bf16x8 b0 = *(const bf16x8*)&Kt[cur][nt * 16 + m][kq];
      bf16x8 b1 = *(const bf16x8*)&Kt[cur][nt * 16 + m][32 + kq];
      f32x4 sa = (f32x4){0.f, 0.f, 0.f, 0.f};
      sa = __builtin_amdgcn_mfma_f32_16x16x32_bf16(b0, aq0, sa, 0, 0, 0);
      sa = __builtin_amdgcn_mfma_f32_16x16x32_bf16(b1, aq1, sa, 0, 0, 0);
      s[nt] = sa;
    }

    // ---- causal mask (diagonal tile only): mask where kv > q ----
    if (s0 + 64 > t0) {
      int qrow = t0 + wave * 16 + m;
#pragma unroll
      for (int nt = 0; nt < 4; ++nt) {
#pragma unroll
        for (int r = 0; r < 4; ++r) {
          int kv = s0 + nt * 16 + quad * 4 + r;
          if (kv > qrow) s[nt][r] = -1e30f;
        }
      }
    }

    // ---- P = exp2(S) -> packed b64 store: P[q=m][kv], 4 consecutive kv ----
    bf16(*Pl)[72] = &Kt[nxt][wave * 16];
#pragma unroll
    for (int nt = 0; nt < 4; ++nt) {
      bf16x4 pv;
#pragma unroll
      for (int r = 0; r < 4; ++r) pv[r] = (bf16)exp2f(s[nt][r]);
      *(bf16x4*)&Pl[m][nt * 16 + quad * 4] = pv;
    }

    // ---- O += P V ; l += P * ones (in-wave P round-trip, no barrier) ----
#pragma unroll
    for (int ch = 0; ch < 2; ++ch) {
      bf16x8 ap = *(const bf16x8*)&Pl[m][ch * 32 + kq];
      lsum = __builtin_amdgcn_mfma_f32_16x16x32_bf16(ap, onesb, lsum, 0, 0, 0);
#pragma unroll
      for (int nt = 0; nt < 4; ++nt) {
        bf16x8 bv = *(const bf16x8*)&Vt[cur][nt * 16 + m][ch * 32 + kq];
        o[nt] = __builtin_amdgcn_mfma_f32_16x16x32_bf16(ap, bv, o[nt], 0, 0, 0);
      }
    }

    // ---- stage next tile into buf[nxt] own-wave rows (after P consumed) ----
    if (i + 1 < niter) {
      *(bf16x8*)&Kt[nxt][r_][seg * 16] = k0;
      *(bf16x8*)&Kt[nxt][r_][seg * 16 + 8] = k1;
      *(bf16x8*)&Vt[nxt][r_][seg * 16] = v0;
      *(bf16x8*)&Vt[nxt][r_][seg * 16 + 8] = v1;
    }
  }

  // ---- epilogue ----
  int rl0 = wave * 16 + quad * 4;
  if (g == 0) {  // single chunk: write normalized output directly
    float* op = out + ((size_t)b * Tt + t0) * 64;
#pragma unroll
    for (int r = 0; r < 4; ++r) {
      float inv = 1.0f / lsum[r];
#pragma unroll
      for (int nt = 0; nt < 4; ++nt)
        op[(size_t)(rl0 + r) * 64 + nt * 16 + m] = o[nt][r] * inv;
    }
  } else {
    int p = b * 288 + 4 * g * (g + 1) + (qi - 8 * g) * (g + 1) + c;
    bf16* Op = Opart + (size_t)p * 4096;
#pragma unroll
    for (int r = 0; r < 4; ++r)
#pragma unroll
      for (int nt = 0; nt < 4; ++nt)
        Op[(rl0 + r) * 64 + nt * 16 + m] = (bf16)o[nt][r];
    if (m == 0) {
#pragma unroll
      for (int r = 0; r < 4; ++r) Lpart[p * 64 + rl0 + r] = lsum[r];
    }
  }
}

// ---------------------------------------------------------------------------
// Kernel 3: combine partials (plain sums). qi >= 8 only; 896 blocks.
// ---------------------------------------------------------------------------
__global__ __launch_bounds__(256) void combine_kernel(const bf16* __restrict__ Opart,
                                                      const float* __restrict__ Lpart,
                                                      float* __restrict__ out) {
  int blk = blockIdx.x;
  int b = blk / 224, rem = blk % 224;
  int qi = 8 + (rem >> 2), rq = rem & 3;
  int g = qi >> 3, nc = g + 1;
  int pb = b * 288 + 4 * g * (g + 1) + (qi - 8 * g) * (g + 1);
  int t = threadIdx.x, col = t & 63, rl = t >> 6;
#pragma unroll
  for (int rr = 0; rr < 4; ++rr) {
    int row64 = rq * 16 + rl * 4 + rr;
    float L = 0.f, acc = 0.f;
    for (int cc = 0; cc < nc; ++cc) {
      L += Lpart[(pb + cc) * 64 + row64];
      acc += (float)Opart[(size_t)(pb + cc) * 4096 + row64 * 64 + col];
    }
    out[((size_t)b * Tt + qi * 64 + row64) * 64 + col] = acc / L;
  }
}

// ---------------------------------------------------------------------------
extern "C" void kernel_launch(void* const* d_in, const int* in_sizes, int n_in,
                              void* d_out, int out_size, void* d_ws, size_t ws_size,
                              hipStream_t stream) {
  const float* x = (const float*)d_in[0];
  const float* Wk = (const float*)d_in[1];
  const float* Wq = (const float*)d_in[2];
  const float* Wv = (const float*)d_in[3];
  float* out = (float*)d_out;

  char* w = (char*)d_ws;
  bf16* wt = (bf16*)w;                      // 196608
  bf16* Kb = (bf16*)(w + 196608);           // 2097152
  bf16* Qb = (bf16*)(w + 2293760);          // 2097152
  bf16* VTb = (bf16*)(w + 4390912);         // 2097152
  bf16* Opart = (bf16*)(w + 6488064);       // 9437184
  float* Lpart = (float*)(w + 15925248);    // 294912

  wt_kernel<<<384, 256, 0, stream>>>(Wk, Wq, Wv, wt);
  proj_kernel<<<1024, 256, 0, stream>>>(x, wt, Kb, Qb, VTb);
  attn_kernel<<<1152, 256, 0, stream>>>(Qb, Kb, VTb, Opart, Lpart, out);
  combine_kernel<<<896, 256, 0, stream>>>(Opart, Lpart, out);
}